// Round 1
// baseline (623.273 us; speedup 1.0000x reference)
//
#include <hip/hip_runtime.h>
#include <hip/hip_bf16.h>

#define NTOT (4*256*256)      // 262144 feature rows
#define DIM 384
#define KCL 256               // clusters
#define BM 64                 // rows per block tile
#define BK 32                 // k-step
#define TBS 256               // threads per block
#define GRID_MAIN (NTOT/BM)   // 4096 blocks
#define EPS 1e-12f

// ---------------------------------------------------------------------------
// Pre-pass: L2-normalize cluster centers, store TRANSPOSED: ct[k][j]
// 256 blocks x 64 lanes; block j handles cluster row j.
// ---------------------------------------------------------------------------
__global__ void prep_clusters(const float* __restrict__ cc, float* __restrict__ ct) {
    int j = blockIdx.x;
    int l = threadIdx.x;
    float v[6];
    float ssq = 0.f;
#pragma unroll
    for (int i = 0; i < 6; ++i) {
        v[i] = cc[(size_t)j * DIM + l + 64 * i];
        ssq = fmaf(v[i], v[i], ssq);
    }
#pragma unroll
    for (int off = 32; off >= 1; off >>= 1) ssq += __shfl_xor(ssq, off);
    float inv = 1.0f / fmaxf(sqrtf(ssq), EPS);
#pragma unroll
    for (int i = 0; i < 6; ++i) ct[(size_t)(l + 64 * i) * KCL + j] = v[i] * inv;
}

// ---------------------------------------------------------------------------
// Main: tiled f32 GEMM [BM x 384] x [384 x 256] + row sumsq + argmax + loss
// ---------------------------------------------------------------------------
__launch_bounds__(TBS, 3)
__global__ void kmeans_main(const float* __restrict__ A,   // features [NTOT][384]
                            const float* __restrict__ W,   // weight   [NTOT]
                            const float* __restrict__ CT,  // [384][256] normalized^T
                            const int*   __restrict__ PA,  // [256] pseudo_assignment
                            float* __restrict__ out,       // [2*NTOT+1]
                            float* __restrict__ partial)   // [GRID_MAIN]
{
    __shared__ float As[BK][BM + 4];   // transposed A tile, padded (bank spread)
    __shared__ float Bs[BK][KCL];      // B tile (contiguous rows, conflict-free)
    __shared__ float rowssq[BM];
    __shared__ float lpart[8];

    const int tid = threadIdx.x;
    const int tx  = tid & 31;          // col group 0..31
    const int ty  = tid >> 5;          // row group 0..7
    const int row0 = blockIdx.x * BM;

    // A-load mapping: 8 lanes per row (64B chunks), 2 rows per thread (m, m+32)
    const int am  = tid >> 3;          // 0..31
    const int akq = tid & 7;           // 16B chunk within BK
    // B-load mapping: wave-contiguous 1KB rows
    const int bkr = tid >> 6;          // 0..3
    const int bc  = (tid & 63) * 4;    // col 0..252

    float acc[8][8];
#pragma unroll
    for (int i = 0; i < 8; ++i)
#pragma unroll
        for (int jj = 0; jj < 8; ++jj) acc[i][jj] = 0.f;

    float ssqA = 0.f, ssqB = 0.f;      // row sumsq for rows am, am+32 (akq==0 lanes)

    for (int ks = 0; ks < DIM; ks += BK) {
        // ---- stage A tile (transposed) + accumulate row sumsq ----
        float4 av0 = *(const float4*)&A[(size_t)(row0 + am)      * DIM + ks + 4 * akq];
        float4 av1 = *(const float4*)&A[(size_t)(row0 + am + 32) * DIM + ks + 4 * akq];
#pragma unroll
        for (int w = 0; w < 4; ++w) {
            As[4 * akq + w][am]      = ((const float*)&av0)[w];
            As[4 * akq + w][am + 32] = ((const float*)&av1)[w];
        }
        float s0 = fmaf(av0.x, av0.x, fmaf(av0.y, av0.y, fmaf(av0.z, av0.z, av0.w * av0.w)));
        float s1 = fmaf(av1.x, av1.x, fmaf(av1.y, av1.y, fmaf(av1.z, av1.z, av1.w * av1.w)));
        s0 += __shfl_down(s0, 4); s0 += __shfl_down(s0, 2); s0 += __shfl_down(s0, 1);
        s1 += __shfl_down(s1, 4); s1 += __shfl_down(s1, 2); s1 += __shfl_down(s1, 1);
        if (akq == 0) { ssqA += s0; ssqB += s1; }

        // ---- stage B tile (already [k][j] layout) ----
#pragma unroll
        for (int i = 0; i < 8; ++i) {
            int kr = bkr + 4 * i;
            float4 bv = *(const float4*)&CT[(size_t)(ks + kr) * KCL + bc];
            *(float4*)&Bs[kr][bc] = bv;
        }
        __syncthreads();

        // ---- compute ----
#pragma unroll 8
        for (int k = 0; k < BK; ++k) {
            float4 a0 = *(const float4*)&As[k][ty * 8];
            float4 a1 = *(const float4*)&As[k][ty * 8 + 4];
            float4 b0 = *(const float4*)&Bs[k][tx * 4];
            float4 b1 = *(const float4*)&Bs[k][128 + tx * 4];
            float av[8] = {a0.x, a0.y, a0.z, a0.w, a1.x, a1.y, a1.z, a1.w};
            float bv[8] = {b0.x, b0.y, b0.z, b0.w, b1.x, b1.y, b1.z, b1.w};
#pragma unroll
            for (int i = 0; i < 8; ++i)
#pragma unroll
                for (int jj = 0; jj < 8; ++jj)
                    acc[i][jj] = fmaf(av[i], bv[jj], acc[i][jj]);
        }
        __syncthreads();
    }

    // publish row sumsq
    if (akq == 0) { rowssq[am] = ssqA; rowssq[am + 32] = ssqB; }
    __syncthreads();

    // ---- epilogue: per-row argmax over 256 cols, outputs, loss ----
    float lsum = 0.f;
#pragma unroll
    for (int i = 0; i < 8; ++i) {
        float best = acc[i][0];
        int bidx = tx * 4;
#pragma unroll
        for (int jj = 1; jj < 4; ++jj) {
            float v = acc[i][jj];
            int c = tx * 4 + jj;
            if (v > best) { best = v; bidx = c; }
        }
#pragma unroll
        for (int jj = 4; jj < 8; ++jj) {
            float v = acc[i][jj];
            int c = 128 + tx * 4 + (jj - 4);
            if (v > best) { best = v; bidx = c; }
        }
#pragma unroll
        for (int off = 16; off >= 1; off >>= 1) {
            float ov = __shfl_xor(best, off);
            int   oi = __shfl_xor(bidx, off);
            if (ov > best || (ov == best && oi < bidx)) { best = ov; bidx = oi; }
        }
        if (tx == 0) {
            int r = row0 + ty * 8 + i;
            float inv = 1.0f / fmaxf(sqrtf(rowssq[ty * 8 + i]), EPS);
            out[r]        = (float)bidx;
            out[NTOT + r] = (float)PA[bidx];
            lsum = fmaf(-(best * inv), W[r], lsum);
        }
    }
    if (tx == 0) lpart[ty] = lsum;
    __syncthreads();
    if (tid == 0) {
        float s = 0.f;
#pragma unroll
        for (int t = 0; t < 8; ++t) s += lpart[t];
        partial[blockIdx.x] = s;
    }
}

// ---------------------------------------------------------------------------
// Deterministic final loss reduction: 4096 partials -> mean
// ---------------------------------------------------------------------------
__global__ void loss_reduce(const float* __restrict__ partial, float* __restrict__ out_loss) {
    __shared__ float s[256];
    float v = 0.f;
    for (int i = threadIdx.x; i < GRID_MAIN; i += 256) v += partial[i];
    s[threadIdx.x] = v;
    __syncthreads();
    for (int off = 128; off >= 1; off >>= 1) {
        if ((int)threadIdx.x < off) s[threadIdx.x] += s[threadIdx.x + off];
        __syncthreads();
    }
    if (threadIdx.x == 0) out_loss[0] = s[0] * (1.0f / (float)NTOT);
}

extern "C" void kernel_launch(void* const* d_in, const int* in_sizes, int n_in,
                              void* d_out, int out_size, void* d_ws, size_t ws_size,
                              hipStream_t stream) {
    const float* features = (const float*)d_in[0];
    const float* weight   = (const float*)d_in[1];
    const float* cc       = (const float*)d_in[2];
    const int*   pa       = (const int*)d_in[3];
    float* out = (float*)d_out;

    float* ct      = (float*)d_ws;            // 384*256 f32 = 384 KiB
    float* partial = ct + DIM * KCL;          // 4096 f32

    hipLaunchKernelGGL(prep_clusters, dim3(KCL), dim3(64), 0, stream, cc, ct);
    hipLaunchKernelGGL(kmeans_main, dim3(GRID_MAIN), dim3(TBS), 0, stream,
                       features, weight, ct, pa, out, partial);
    hipLaunchKernelGGL(loss_reduce, dim3(1), dim3(256), 0, stream, partial, out + 2 * NTOT);
}

// Round 2
// 264.502 us; speedup vs baseline: 2.3564x; 2.3564x over previous
//
#include <hip/hip_runtime.h>
#include <hip/hip_bf16.h>

#define NTOT (4*256*256)      // 262144 feature rows
#define DIM 384
#define KCL 256               // clusters
#define BM 64                 // rows per block tile
#define BK 32                 // k-step
#define TBS 256               // threads per block
#define GRID_MAIN (NTOT/BM)   // 4096 blocks
#define EPS 1e-12f

typedef __attribute__((ext_vector_type(8))) _Float16 f16x8;
typedef __attribute__((ext_vector_type(4))) float f32x4;

__device__ __forceinline__ void async_copy16(const void* gptr, void* lptr) {
    __builtin_amdgcn_global_load_lds(
        (const __attribute__((address_space(1))) unsigned int*)gptr,
        (__attribute__((address_space(3))) unsigned int*)lptr, 16, 0, 0);
}

// ---------------------------------------------------------------------------
// Pre-pass: L2-normalize cluster centers, emit fp16 hi/lo splits in [n][k]
// layout (same as input layout -> contiguous writes).
// ---------------------------------------------------------------------------
__global__ void prep_clusters(const float* __restrict__ cc,
                              _Float16* __restrict__ bh, _Float16* __restrict__ bl) {
    int j = blockIdx.x, l = threadIdx.x;   // 256 blocks x 64 lanes
    float v[6]; float ssq = 0.f;
#pragma unroll
    for (int i = 0; i < 6; ++i) { v[i] = cc[j*DIM + l + 64*i]; ssq = fmaf(v[i], v[i], ssq); }
#pragma unroll
    for (int off = 32; off >= 1; off >>= 1) ssq += __shfl_xor(ssq, off);
    float inv = 1.f / fmaxf(sqrtf(ssq), EPS);
#pragma unroll
    for (int i = 0; i < 6; ++i) {
        float x = v[i] * inv;
        _Float16 h  = (_Float16)x;
        _Float16 lo = (_Float16)(x - (float)h);
        bh[j*DIM + l + 64*i] = h;
        bl[j*DIM + l + 64*i] = lo;
    }
}

// ---------------------------------------------------------------------------
// Main: split-fp16 MFMA GEMM [64 x 384] x [384 x 256] (3 passes: ah*bh +
// ah*bl + al*bh, f32 accumulate) + row sumsq + argmax + loss partials.
// ---------------------------------------------------------------------------
__launch_bounds__(TBS)
__global__ void kmeans_main(const float* __restrict__ A,   // features [NTOT][384] f32
                            const float* __restrict__ W,   // weight   [NTOT]
                            const _Float16* __restrict__ Bh, // [256][384] fp16 hi
                            const _Float16* __restrict__ Bl, // [256][384] fp16 lo
                            const int*   __restrict__ PA,  // [256]
                            float* __restrict__ out,       // [2*NTOT+1]
                            float* __restrict__ partial)   // [GRID_MAIN]
{
    __shared__ _Float16 Ah[BM*BK], Al[BM*BK];     // [row][k]  64x32
    __shared__ _Float16 Bhs[KCL*BK], Bls[KCL*BK]; // [n][k]   256x32
    __shared__ float rowssq[BM];
    __shared__ float wval[4][BM];
    __shared__ int   wcol[4][BM];

    const int tid  = threadIdx.x;
    const int wv   = tid >> 6;        // wave 0..3 -> owns cols [64*wv, 64*wv+64)
    const int lane = tid & 63;
    const int g    = lane >> 4;       // k-group 0..3
    const int l15  = lane & 15;
    const int row0 = blockIdx.x * BM;
    const int arow = tid >> 2, achk = tid & 3;   // A loader: row, 8-float chunk

    const float* aptr = A + (size_t)(row0 + arow) * DIM + achk * 8;

    f32x4 acc[4][4];
#pragma unroll
    for (int m = 0; m < 4; ++m)
#pragma unroll
        for (int n = 0; n < 4; ++n) acc[m][n] = (f32x4){0.f, 0.f, 0.f, 0.f};

    float ssq = 0.f;

    for (int ks = 0; ks < DIM; ks += BK) {
        // ---- stage B (hi/lo) via async global->LDS, layout [n][32] fp16 ----
#pragma unroll
        for (int i = 0; i < 4; ++i) {
            int nrow = i * 64 + (tid >> 2);
            async_copy16(Bh + (size_t)nrow * DIM + ks + achk * 8,
                         (_Float16*)Bhs + i * 2048 + tid * 8);
            async_copy16(Bl + (size_t)nrow * DIM + ks + achk * 8,
                         (_Float16*)Bls + i * 2048 + tid * 8);
        }
        // ---- stage A: f32 load, split to fp16 hi/lo, sumsq for free ----
        float4 a0 = *(const float4*)(aptr + ks);
        float4 a1 = *(const float4*)(aptr + ks + 4);
        float av[8] = {a0.x, a0.y, a0.z, a0.w, a1.x, a1.y, a1.z, a1.w};
        f16x8 h8, l8;
#pragma unroll
        for (int w = 0; w < 8; ++w) {
            _Float16 hh = (_Float16)av[w];
            h8[w] = hh;
            l8[w] = (_Float16)(av[w] - (float)hh);
            ssq = fmaf(av[w], av[w], ssq);
        }
        *(f16x8*)&Ah[tid * 8] = h8;   // == [arow][achk*8], contiguous per wave
        *(f16x8*)&Al[tid * 8] = l8;
        __syncthreads();

        // ---- fragments (all contiguous-1KB wave reads: conflict-free) ----
        f16x8 ahf[4], alf[4], bhf[4], blf[4];
#pragma unroll
        for (int m = 0; m < 4; ++m) {
            ahf[m] = *(const f16x8*)&Ah[(16*m + l15) * BK + 8*g];
            alf[m] = *(const f16x8*)&Al[(16*m + l15) * BK + 8*g];
        }
#pragma unroll
        for (int n = 0; n < 4; ++n) {
            int cn = wv * 64 + 16*n + l15;
            bhf[n] = *(const f16x8*)&Bhs[cn * BK + 8*g];
            blf[n] = *(const f16x8*)&Bls[cn * BK + 8*g];
        }
        // ---- 3 split passes, 48 MFMA ----
#pragma unroll
        for (int m = 0; m < 4; ++m)
#pragma unroll
            for (int n = 0; n < 4; ++n)
                acc[m][n] = __builtin_amdgcn_mfma_f32_16x16x32_f16(ahf[m], bhf[n], acc[m][n], 0, 0, 0);
#pragma unroll
        for (int m = 0; m < 4; ++m)
#pragma unroll
            for (int n = 0; n < 4; ++n)
                acc[m][n] = __builtin_amdgcn_mfma_f32_16x16x32_f16(ahf[m], blf[n], acc[m][n], 0, 0, 0);
#pragma unroll
        for (int m = 0; m < 4; ++m)
#pragma unroll
            for (int n = 0; n < 4; ++n)
                acc[m][n] = __builtin_amdgcn_mfma_f32_16x16x32_f16(alf[m], bhf[n], acc[m][n], 0, 0, 0);
        __syncthreads();
    }

    // ---- row sumsq: 4 loader threads per row ----
    ssq += __shfl_xor(ssq, 1);
    ssq += __shfl_xor(ssq, 2);
    if (achk == 0) rowssq[arow] = ssq;

    // ---- per-row argmax. acc[m][n][j] = S[16m+4g+j][64wv+16n+l15] ----
#pragma unroll
    for (int m = 0; m < 4; ++m) {
#pragma unroll
        for (int j = 0; j < 4; ++j) {
            float best = acc[m][0][j];
            int   bc   = wv * 64 + l15;
#pragma unroll
            for (int n = 1; n < 4; ++n) {
                float v = acc[m][n][j];
                int   c = wv * 64 + 16*n + l15;
                if (v > best) { best = v; bc = c; }
            }
#pragma unroll
            for (int off = 1; off < 16; off <<= 1) {
                float ov = __shfl_xor(best, off);
                int   oc = __shfl_xor(bc, off);
                if (ov > best || (ov == best && oc < bc)) { best = ov; bc = oc; }
            }
            if (l15 == 0) { wval[wv][16*m + 4*g + j] = best; wcol[wv][16*m + 4*g + j] = bc; }
        }
    }
    __syncthreads();

    // ---- combine 4 waves, write outputs, block loss partial ----
    if (tid < BM) {
        int r = tid;
        float best = wval[0][r]; int bc = wcol[0][r];
#pragma unroll
        for (int w = 1; w < 4; ++w) {
            float ov = wval[w][r]; int oc = wcol[w][r];
            if (ov > best || (ov == best && oc < bc)) { best = ov; bc = oc; }
        }
        float inv = 1.f / fmaxf(sqrtf(rowssq[r]), EPS);
        out[row0 + r]        = (float)bc;
        out[NTOT + row0 + r] = (float)PA[bc];
        float lsum = -(best * inv) * W[row0 + r];
#pragma unroll
        for (int off = 32; off >= 1; off >>= 1) lsum += __shfl_xor(lsum, off);
        if (tid == 0) partial[blockIdx.x] = lsum;
    }
}

// ---------------------------------------------------------------------------
// Deterministic final loss reduction: 4096 partials -> mean
// ---------------------------------------------------------------------------
__global__ void loss_reduce(const float* __restrict__ partial, float* __restrict__ out_loss) {
    __shared__ float s[256];
    float v = 0.f;
    for (int i = threadIdx.x; i < GRID_MAIN; i += 256) v += partial[i];
    s[threadIdx.x] = v;
    __syncthreads();
    for (int off = 128; off >= 1; off >>= 1) {
        if ((int)threadIdx.x < off) s[threadIdx.x] += s[threadIdx.x + off];
        __syncthreads();
    }
    if (threadIdx.x == 0) out_loss[0] = s[0] * (1.0f / (float)NTOT);
}

extern "C" void kernel_launch(void* const* d_in, const int* in_sizes, int n_in,
                              void* d_out, int out_size, void* d_ws, size_t ws_size,
                              hipStream_t stream) {
    const float* features = (const float*)d_in[0];
    const float* weight   = (const float*)d_in[1];
    const float* cc       = (const float*)d_in[2];
    const int*   pa       = (const int*)d_in[3];
    float* out = (float*)d_out;

    _Float16* bh = (_Float16*)d_ws;               // 256*384 fp16 = 192 KiB
    _Float16* bl = bh + KCL * DIM;                // 192 KiB
    float* partial = (float*)(bl + KCL * DIM);    // 4096 f32

    hipLaunchKernelGGL(prep_clusters, dim3(KCL), dim3(64), 0, stream, cc, bh, bl);
    hipLaunchKernelGGL(kmeans_main, dim3(GRID_MAIN), dim3(TBS), 0, stream,
                       features, weight, bh, bl, pa, out, partial);
    hipLaunchKernelGGL(loss_reduce, dim3(1), dim3(256), 0, stream, partial, out + 2 * NTOT);
}

// Round 3
// 250.216 us; speedup vs baseline: 2.4909x; 1.0571x over previous
//
#include <hip/hip_runtime.h>
#include <hip/hip_bf16.h>

#define NTOT (4*256*256)      // 262144 feature rows
#define DIM 384
#define KCL 256               // clusters
#define BM 64                 // rows per block tile
#define BK 32                 // k-step
#define TBS 256               // threads per block
#define GRID_MAIN (NTOT/BM)   // 4096 blocks
#define NT (DIM/BK)           // 12 K-steps
#define EPS 1e-12f

// byte offsets inside one 40 KiB staging buffer
#define AH_OFF 0              // A hi   : 64 rows x 4 chunks x 16B = 4 KiB
#define AL_OFF 4096           // A lo   : 4 KiB
#define BH_OFF 8192           // B hi   : 256 rows x 4 chunks x 16B = 16 KiB
#define BL_OFF 24576          // B lo   : 16 KiB
#define BUF_BYTES 40960       // two buffers = 81920 B = exactly 160 KiB/2

typedef __attribute__((ext_vector_type(8))) _Float16 f16x8;
typedef __attribute__((ext_vector_type(4))) float f32x4;

__device__ __forceinline__ void async_copy16(const void* gptr, void* lptr) {
    __builtin_amdgcn_global_load_lds(
        (const __attribute__((address_space(1))) unsigned int*)gptr,
        (__attribute__((address_space(3))) unsigned int*)lptr, 16, 0, 0);
}

// ---------------------------------------------------------------------------
// Pre-pass: L2-normalize cluster centers, emit fp16 hi/lo splits in [n][k]
// ---------------------------------------------------------------------------
__global__ void prep_clusters(const float* __restrict__ cc,
                              _Float16* __restrict__ bh, _Float16* __restrict__ bl) {
    int j = blockIdx.x, l = threadIdx.x;   // 256 blocks x 64 lanes
    float v[6]; float ssq = 0.f;
#pragma unroll
    for (int i = 0; i < 6; ++i) { v[i] = cc[j*DIM + l + 64*i]; ssq = fmaf(v[i], v[i], ssq); }
#pragma unroll
    for (int off = 32; off >= 1; off >>= 1) ssq += __shfl_xor(ssq, off);
    float inv = 1.f / fmaxf(sqrtf(ssq), EPS);
#pragma unroll
    for (int i = 0; i < 6; ++i) {
        float x = v[i] * inv;
        _Float16 h  = (_Float16)x;
        _Float16 lo = (_Float16)(x - (float)h);
        bh[j*DIM + l + 64*i] = h;
        bl[j*DIM + l + 64*i] = lo;
    }
}

// ---------------------------------------------------------------------------
// Main: split-fp16 MFMA GEMM, 2-phase double-buffered pipeline, swizzled LDS.
// Chunk (row, g) -> 16B slot  row*4 + (g ^ ((row>>1)&3)).
// ---------------------------------------------------------------------------
__global__ __launch_bounds__(TBS)
void kmeans_main(const float* __restrict__ A,    // features [NTOT][384] f32
                 const float* __restrict__ W,    // weight   [NTOT]
                 const _Float16* __restrict__ Bh,// [256][384] fp16 hi
                 const _Float16* __restrict__ Bl,// [256][384] fp16 lo
                 const int*   __restrict__ PA,   // [256]
                 float* __restrict__ out,        // [2*NTOT+1]
                 float* __restrict__ partial)    // [GRID_MAIN]
{
    __shared__ unsigned char smem[2 * BUF_BYTES];

    const int tid  = threadIdx.x;
    const int wv   = tid >> 6;        // wave 0..3 -> cols [64*wv, 64*wv+64)
    const int lane = tid & 63;
    const int g    = lane >> 4;       // k-group 0..3
    const int l15  = lane & 15;
    const int sw   = (l15 >> 1) & 3;  // read-side swizzle term
    const int row0 = blockIdx.x * BM;
    const int arow = tid >> 2, achk = tid & 3;        // A loader mapping
    const int bg   = (tid & 3) ^ ((tid >> 3) & 3);    // B stage chunk index
    // A ds_write byte offset (swizzled slot for chunk (arow, achk))
    const int awb  = (((arow << 2) + (achk ^ ((arow >> 1) & 3))) << 4);
    // fragment read base offsets (bytes)
    const int fa   = l15 * 64 + ((g ^ sw) << 4);      // + m*1024
    const int fb   = wv * 4096 + fa;                  // + n*1024

    const float* aptr = A + (size_t)(row0 + arow) * DIM + achk * 8;

    f32x4 acc[4][4];
#pragma unroll
    for (int m = 0; m < 4; ++m)
#pragma unroll
        for (int n = 0; n < 4; ++n) acc[m][n] = (f32x4){0.f, 0.f, 0.f, 0.f};
    float ssq = 0.f;

    auto stageB = [&](int ks, unsigned char* buf) {
#pragma unroll
        for (int i = 0; i < 4; ++i) {
            int row = i * 64 + (tid >> 2);
            async_copy16(Bh + (size_t)row * DIM + ks + 8 * bg,
                         buf + BH_OFF + ((i * 256 + tid) << 4));
            async_copy16(Bl + (size_t)row * DIM + ks + 8 * bg,
                         buf + BL_OFF + ((i * 256 + tid) << 4));
        }
    };
    auto writeA = [&](const float4& x0, const float4& x1, unsigned char* buf) {
        float av[8] = {x0.x, x0.y, x0.z, x0.w, x1.x, x1.y, x1.z, x1.w};
        f16x8 h8, l8;
#pragma unroll
        for (int w = 0; w < 8; ++w) {
            _Float16 hh = (_Float16)av[w];
            h8[w] = hh;
            l8[w] = (_Float16)(av[w] - (float)hh);
            ssq = fmaf(av[w], av[w], ssq);
        }
        *(f16x8*)(buf + AH_OFF + awb) = h8;
        *(f16x8*)(buf + AL_OFF + awb) = l8;
    };
    auto compute = [&](const unsigned char* buf) {
        f16x8 ahf[4], alf[4], bhf[4], blf[4];
#pragma unroll
        for (int m = 0; m < 4; ++m) {
            ahf[m] = *(const f16x8*)(buf + AH_OFF + fa + m * 1024);
            alf[m] = *(const f16x8*)(buf + AL_OFF + fa + m * 1024);
        }
#pragma unroll
        for (int n = 0; n < 4; ++n) {
            bhf[n] = *(const f16x8*)(buf + BH_OFF + fb + n * 1024);
            blf[n] = *(const f16x8*)(buf + BL_OFF + fb + n * 1024);
        }
#pragma unroll
        for (int m = 0; m < 4; ++m)
#pragma unroll
            for (int n = 0; n < 4; ++n)
                acc[m][n] = __builtin_amdgcn_mfma_f32_16x16x32_f16(ahf[m], bhf[n], acc[m][n], 0, 0, 0);
#pragma unroll
        for (int m = 0; m < 4; ++m)
#pragma unroll
            for (int n = 0; n < 4; ++n)
                acc[m][n] = __builtin_amdgcn_mfma_f32_16x16x32_f16(ahf[m], blf[n], acc[m][n], 0, 0, 0);
#pragma unroll
        for (int m = 0; m < 4; ++m)
#pragma unroll
            for (int n = 0; n < 4; ++n)
                acc[m][n] = __builtin_amdgcn_mfma_f32_16x16x32_f16(alf[m], bhf[n], acc[m][n], 0, 0, 0);
    };

    // ---- prologue: stage tile 0 into buf0 ----
    {
        float4 p0 = *(const float4*)(aptr);
        float4 p1 = *(const float4*)(aptr + 4);
        stageB(0, smem);
        writeA(p0, p1, smem);          // waits only on the 2 A loads (vmcnt(8))
        __syncthreads();               // drains gl_lds + ds_write
    }

    // ---- 2-phase main loop (static buffer selection) ----
    for (int t = 0; t < NT; t += 2) {
        {   // even: compute buf0, stage t+1 into buf1  (t+1 <= 11 always)
            const int ksn = (t + 1) * BK;
            float4 n0 = *(const float4*)(aptr + ksn);
            float4 n1 = *(const float4*)(aptr + ksn + 4);
            stageB(ksn, smem + BUF_BYTES);
            compute(smem);
            writeA(n0, n1, smem + BUF_BYTES);
            __syncthreads();
        }
        {   // odd: compute buf1, stage t+2 into buf0 (skip on last)
            if (t + 2 < NT) {
                const int ksn = (t + 2) * BK;
                float4 n0 = *(const float4*)(aptr + ksn);
                float4 n1 = *(const float4*)(aptr + ksn + 4);
                stageB(ksn, smem);
                compute(smem + BUF_BYTES);
                writeA(n0, n1, smem);
            } else {
                compute(smem + BUF_BYTES);
            }
            __syncthreads();
        }
    }

    // ---- epilogue (overlay scratch on buf0; all compute done) ----
    float* rowssq = (float*)smem;                 // 256 B
    float* wvalp  = (float*)(smem + 256);         // 1 KiB
    int*   wcolp  = (int*)(smem + 1280);          // 1 KiB

    ssq += __shfl_xor(ssq, 1);
    ssq += __shfl_xor(ssq, 2);
    if (achk == 0) rowssq[arow] = ssq;

    // per-row argmax. acc[m][n][j] = S[16m + 4g + j][64wv + 16n + l15]
#pragma unroll
    for (int m = 0; m < 4; ++m) {
#pragma unroll
        for (int j = 0; j < 4; ++j) {
            float best = acc[m][0][j];
            int   bc   = wv * 64 + l15;
#pragma unroll
            for (int n = 1; n < 4; ++n) {
                float v = acc[m][n][j];
                int   c = wv * 64 + 16 * n + l15;
                if (v > best) { best = v; bc = c; }
            }
#pragma unroll
            for (int off = 1; off < 16; off <<= 1) {
                float ov = __shfl_xor(best, off);
                int   oc = __shfl_xor(bc, off);
                if (ov > best || (ov == best && oc < bc)) { best = ov; bc = oc; }
            }
            if (l15 == 0) {
                wvalp[wv * BM + 16 * m + 4 * g + j] = best;
                wcolp[wv * BM + 16 * m + 4 * g + j] = bc;
            }
        }
    }
    __syncthreads();

    if (tid < BM) {
        int r = tid;
        float best = wvalp[r]; int bc = wcolp[r];
#pragma unroll
        for (int w = 1; w < 4; ++w) {
            float ov = wvalp[w * BM + r]; int oc = wcolp[w * BM + r];
            if (ov > best || (ov == best && oc < bc)) { best = ov; bc = oc; }
        }
        float inv = 1.f / fmaxf(sqrtf(rowssq[r]), EPS);
        out[row0 + r]        = (float)bc;
        out[NTOT + row0 + r] = (float)PA[bc];
        float lsum = -(best * inv) * W[row0 + r];
#pragma unroll
        for (int off = 32; off >= 1; off >>= 1) lsum += __shfl_xor(lsum, off);
        if (tid == 0) partial[blockIdx.x] = lsum;
    }
}

// ---------------------------------------------------------------------------
// Deterministic final loss reduction: 4096 partials -> mean
// ---------------------------------------------------------------------------
__global__ void loss_reduce(const float* __restrict__ partial, float* __restrict__ out_loss) {
    __shared__ float s[256];
    float v = 0.f;
    for (int i = threadIdx.x; i < GRID_MAIN; i += 256) v += partial[i];
    s[threadIdx.x] = v;
    __syncthreads();
    for (int off = 128; off >= 1; off >>= 1) {
        if ((int)threadIdx.x < off) s[threadIdx.x] += s[threadIdx.x + off];
        __syncthreads();
    }
    if (threadIdx.x == 0) out_loss[0] = s[0] * (1.0f / (float)NTOT);
}

extern "C" void kernel_launch(void* const* d_in, const int* in_sizes, int n_in,
                              void* d_out, int out_size, void* d_ws, size_t ws_size,
                              hipStream_t stream) {
    const float* features = (const float*)d_in[0];
    const float* weight   = (const float*)d_in[1];
    const float* cc       = (const float*)d_in[2];
    const int*   pa       = (const int*)d_in[3];
    float* out = (float*)d_out;

    _Float16* bh = (_Float16*)d_ws;               // 192 KiB
    _Float16* bl = bh + KCL * DIM;                // 192 KiB
    float* partial = (float*)(bl + KCL * DIM);    // 16 KiB

    hipLaunchKernelGGL(prep_clusters, dim3(KCL), dim3(64), 0, stream, cc, bh, bl);
    hipLaunchKernelGGL(kmeans_main, dim3(GRID_MAIN), dim3(TBS), 0, stream,
                       features, weight, bh, bl, pa, out, partial);
    hipLaunchKernelGGL(loss_reduce, dim3(1), dim3(256), 0, stream, partial, out + 2 * NTOT);
}